// Round 4
// baseline (2307.109 us; speedup 1.0000x reference)
//
#include <hip/hip_runtime.h>
#include <hip/hip_bf16.h>
#include <stdint.h>

#define N_TOK   8192
#define DDIM    1024
#define HDIM    2048
#define NEXP    8
#define NSLOTS  16384

// work-queue segments
#define X_ITEMS    128              // x:   8.39M elems / 65536
#define W1_ITEMS   256              // w1: 16.78M / 65536
#define W2_ITEMS   256              // w2: 16.78M / 65536
#define SEGA_ITEMS (X_ITEMS + W1_ITEMS)   // 384
#define SEGB_ITEMS W2_ITEMS               // 256
#define GEMM0      (1 + SEGA_ITEMS + SEGB_ITEMS)  // 641

typedef float f32x4 __attribute__((ext_vector_type(4)));
typedef __bf16 b16x8 __attribute__((ext_vector_type(8)));

__device__ __forceinline__ unsigned short f2bf(float f) {
  union { float f; uint32_t u; } x; x.f = f;
  uint32_t r = (x.u + 0x7FFFu + ((x.u >> 16) & 1u)) >> 16;
  return (unsigned short)r;
}

#define GLD16(gp, lp) __builtin_amdgcn_global_load_lds( \
    (const __attribute__((address_space(1))) void*)(gp), \
    (__attribute__((address_space(3))) void*)(lp), 16, 0, 0)

// ---- init: zero counters + d_out (fp32 atomic-accum target) ----
__global__ void k_zero(float* __restrict__ out, int* __restrict__ ctrs) {
  if (blockIdx.x == 0 && threadIdx.x < 16) ctrs[threadIdx.x] = 0;
  int stride = gridDim.x * blockDim.x;
  int n4 = N_TOK * DDIM / 4;
  for (int i = blockIdx.x * blockDim.x + threadIdx.x; i < n4; i += stride)
    ((float4*)out)[i] = (float4){0.f, 0.f, 0.f, 0.f};
}

__device__ __forceinline__ void block_wait(int* p, int need) {
  if (threadIdx.x == 0)
    while (__hip_atomic_load(p, __ATOMIC_ACQUIRE, __HIP_MEMORY_SCOPE_AGENT) < need)
      __builtin_amdgcn_s_sleep(8);
  __syncthreads();
  __threadfence();
}

// ---------- grouped GEMM tile (NT): C[r,c] = A[r,:K].B[c,:K), 128x128, BK=64 ----------
// 4 waves, each 64x64 (4x4 frags of 16x16x32 bf16). LDS XOR-swizzle byte^((row&7)<<4);
// staged via global_load_lds with inverse swizzle pre-applied to the GLOBAL source.
// K-loop: reads(kt) -> sync(lgkm0) -> stage(kt+1) -> MFMA -> sync(vmcnt0): the stage DMA
// lands only after all waves' reads completed (barrier), MFMA-ks1 hides part of its latency.
// EPI=0: hid = relu(acc)^2 as bf16.  EPI=1: atomicAdd(out[token], ew[slot]*acc) (2 commutative
// adds per element -> deterministic).
template<int K, int NCOLS, int CT, bool GATHER, int EPI>
__device__ __forceinline__ void gemm_tile(
    const unsigned short* __restrict__ A, const unsigned short* __restrict__ B,
    unsigned short* __restrict__ Chid, float* __restrict__ out,
    const float* __restrict__ ew, const int* __restrict__ slot_of_pos,
    int e, int rt, int ct, int cnt, int off,
    unsigned short* ldsA, unsigned short* ldsB)
{
  const int t = threadIdx.x, lane = t & 63, wid = t >> 6;
  const unsigned short* Bexp = B + (size_t)e * NCOLS * K;

  const unsigned short* aSrc[4];
  const unsigned short* bSrc[4];
  unsigned short *aDst[4], *bDst[4];
#pragma unroll
  for (int j = 0; j < 4; ++j) {
    const int chunk = j * 4 + wid;                 // 0..15
    const int row   = chunk * 8 + (lane >> 3);     // LDS row 0..127
    const int qcol  = ((lane & 7) * 16) ^ ((row & 7) << 4);  // pre-swizzled byte in row
    int pr  = rt * 128 + row;
    int prc = pr < cnt ? pr : 0;
    if constexpr (GATHER) {
      int tok = slot_of_pos[off + prc] >> 1;       // slot -> token
      aSrc[j] = A + (size_t)tok * K + (qcol >> 1);
    } else {
      aSrc[j] = A + (size_t)(off + prc) * K + (qcol >> 1);
    }
    bSrc[j] = Bexp + (size_t)(ct * 128 + row) * K + (qcol >> 1);
    aDst[j] = ldsA + chunk * 512;
    bDst[j] = ldsB + chunk * 512;
  }

  const int wr = wid >> 1, wc = wid & 1;
  const int kq = (lane >> 4) * 16;
  int aByte[4], bByte[4], aXor[4], bXor[4];
#pragma unroll
  for (int m = 0; m < 4; ++m) {
    int row = wr * 64 + m * 16 + (lane & 15);
    aByte[m] = row * 128; aXor[m] = (row & 7) << 4;
    int col = wc * 64 + m * 16 + (lane & 15);
    bByte[m] = col * 128; bXor[m] = (col & 7) << 4;
  }

  f32x4 acc[4][4];
#pragma unroll
  for (int m = 0; m < 4; ++m)
#pragma unroll
    for (int n = 0; n < 4; ++n) acc[m][n] = (f32x4){0.f, 0.f, 0.f, 0.f};

  // prologue: stage kt=0
#pragma unroll
  for (int j = 0; j < 4; ++j) { GLD16(aSrc[j], aDst[j]); GLD16(bSrc[j], bDst[j]); }
  __syncthreads();

  constexpr int KT = K / 64;
  for (int kt = 0; kt < KT; ++kt) {
    b16x8 a0[4], b0[4], a1[4], b1[4];
#pragma unroll
    for (int m = 0; m < 4; ++m) {
      a0[m] = *(const b16x8*)((const char*)ldsA + aByte[m] + (kq ^ aXor[m]));
      b0[m] = *(const b16x8*)((const char*)ldsB + bByte[m] + (kq ^ bXor[m]));
    }
    // ks=0 MFMAs (keeps peak live regs ~40)
#pragma unroll
    for (int m = 0; m < 4; ++m)
#pragma unroll
      for (int n = 0; n < 4; ++n)
        acc[m][n] = __builtin_amdgcn_mfma_f32_16x16x32_bf16(a0[m], b0[n], acc[m][n], 0, 0, 0);
#pragma unroll
    for (int m = 0; m < 4; ++m) {
      a1[m] = *(const b16x8*)((const char*)ldsA + aByte[m] + ((64 + kq) ^ aXor[m]));
      b1[m] = *(const b16x8*)((const char*)ldsB + bByte[m] + ((64 + kq) ^ bXor[m]));
    }
    __syncthreads();                 // lgkm(0): all waves' reads done; vmcnt already 0
    if (kt + 1 < KT) {
#pragma unroll
      for (int j = 0; j < 4; ++j) {
        GLD16(aSrc[j] + (kt + 1) * 64, aDst[j]);
        GLD16(bSrc[j] + (kt + 1) * 64, bDst[j]);
      }
    }
#pragma unroll
    for (int m = 0; m < 4; ++m)
#pragma unroll
      for (int n = 0; n < 4; ++n)
        acc[m][n] = __builtin_amdgcn_mfma_f32_16x16x32_bf16(a1[m], b1[n], acc[m][n], 0, 0, 0);
    __syncthreads();                 // vmcnt(0): next tile landed
  }

  // epilogue: C/D layout col=lane&15, row=(lane>>4)*4+r (m89-verified)
  const int rbase = rt * 128 + wr * 64 + (lane >> 4) * 4;
  const int cbase = ct * 128 + wc * 64 + (lane & 15);
#pragma unroll
  for (int m = 0; m < 4; ++m) {
#pragma unroll
    for (int r = 0; r < 4; ++r) {
      int pr = rbase + m * 16 + r;
      if (pr < cnt) {
        if constexpr (EPI == 0) {
          unsigned short* crow = Chid + (size_t)(off + pr) * NCOLS + cbase;
#pragma unroll
          for (int n = 0; n < 4; ++n) {
            float v = acc[m][n][r];
            v = v > 0.f ? v * v : 0.f;
            crow[n * 16] = f2bf(v);
          }
        } else {
          int slot = slot_of_pos[off + pr];
          float w = ew[slot];
          float* orow = out + (size_t)(slot >> 1) * DDIM + cbase;
#pragma unroll
          for (int n = 0; n < 4; ++n)
            atomicAdd(&orow[n * 16], w * acc[m][n][r]);
        }
      }
    }
  }
}

// ---------------- the mega persistent kernel ----------------
__global__ __launch_bounds__(256, 4)
void k_moe(const float* __restrict__ x, const int* __restrict__ eidx,
           const float* __restrict__ ew, const float* __restrict__ w1,
           const float* __restrict__ w2, float* __restrict__ out,
           unsigned short* __restrict__ xb, unsigned short* __restrict__ w1b,
           unsigned short* __restrict__ w2b, unsigned short* __restrict__ hid,
           int* __restrict__ counts, int* __restrict__ offsets,
           int* __restrict__ slot_of_pos, int* __restrict__ ctrs)
{
  __shared__ unsigned short ldsA[128 * 64];
  __shared__ unsigned short ldsB[128 * 64];
  __shared__ int sItem;
  __shared__ int sc[NEXP], scur[NEXP];

  int* qctr       = ctrs + 0;
  int* route_done = ctrs + 1;
  int* segA_done  = ctrs + 2;
  int* segB_done  = ctrs + 3;
  int* upDone     = ctrs + 4;   // [8]

  const int t = threadIdx.x;

  while (true) {
    __syncthreads();
    if (t == 0) sItem = atomicAdd(qctr, 1);
    __syncthreads();
    const int idx = sItem;

    if (idx == 0) {
      // ---- routing ----
      if (t < NEXP) sc[t] = 0;
      __syncthreads();
      for (int s = t; s < NSLOTS; s += 256) atomicAdd(&sc[eidx[s]], 1);
      __syncthreads();
      if (t == 0) {
        int o = 0;
        for (int q = 0; q < NEXP; ++q) { offsets[q] = o; scur[q] = o; o += sc[q]; }
      }
      __syncthreads();
      for (int s = t; s < NSLOTS; s += 256) {
        int e = eidx[s];
        int p = atomicAdd(&scur[e], 1);
        slot_of_pos[p] = s;
      }
      if (t < NEXP) counts[t] = sc[t];
      __threadfence();
      __syncthreads();
      if (t == 0) atomicAdd(route_done, 1);
      continue;
    }

    if (idx < GEMM0) {
      // ---- fp32 -> bf16 conversion chunk (65536 elems) ----
      const float* s; unsigned short* d; int cl; int* done;
      if (idx <= X_ITEMS)                 { s = x;  d = xb;  cl = idx - 1;               done = segA_done; }
      else if (idx <= SEGA_ITEMS)         { s = w1; d = w1b; cl = idx - 1 - X_ITEMS;     done = segA_done; }
      else                                { s = w2; d = w2b; cl = idx - 1 - SEGA_ITEMS;  done = segB_done; }
      size_t base8 = (size_t)cl * 8192;   // 8-elem groups
      for (int i = t; i < 8192; i += 256) {
        size_t g8 = base8 + i;
        float4 a = ((const float4*)s)[2 * g8];
        float4 b = ((const float4*)s)[2 * g8 + 1];
        union { unsigned short u[8]; uint4 v; } o;
        o.u[0] = f2bf(a.x); o.u[1] = f2bf(a.y); o.u[2] = f2bf(a.z); o.u[3] = f2bf(a.w);
        o.u[4] = f2bf(b.x); o.u[5] = f2bf(b.y); o.u[6] = f2bf(b.z); o.u[7] = f2bf(b.w);
        ((uint4*)d)[g8] = o.v;
      }
      __threadfence();
      __syncthreads();
      if (t == 0) atomicAdd(done, 1);
      continue;
    }

    // ---- GEMM tiles: need routing tables ----
    block_wait(route_done, 1);
    int cnts[NEXP], offs[NEXP], prU[NEXP + 1], prD[NEXP + 1];
    prU[0] = 0; prD[0] = 0;
#pragma unroll
    for (int q = 0; q < NEXP; ++q) {
      int c = __builtin_amdgcn_readfirstlane(counts[q]);
      int o = __builtin_amdgcn_readfirstlane(offsets[q]);
      cnts[q] = c; offs[q] = o;
      int rtn = (c + 127) >> 7;
      prU[q + 1] = prU[q] + rtn * (HDIM / 128);
      prD[q + 1] = prD[q] + rtn * (DDIM / 128);
    }
    const int NU = prU[NEXP], ND = prD[NEXP];
    const int g = idx - GEMM0;
    if (g >= NU + ND) break;

    if (g < NU) {
      // ---- up tile: hid = relu(x @ w1^T)^2 ----
      block_wait(segA_done, SEGA_ITEMS);
      int e = 0;
#pragma unroll
      for (int q = 1; q < NEXP; ++q) e += (g >= prU[q]);
      int base = 0, cnt = 0, off = 0;
#pragma unroll
      for (int q = 0; q < NEXP; ++q)
        if (e == q) { base = prU[q]; cnt = cnts[q]; off = offs[q]; }
      int local = g - base;
      int rt = local / (HDIM / 128), ct = local % (HDIM / 128);
      gemm_tile<DDIM, HDIM, HDIM / 128, true, 0>(
          xb, w1b, hid, nullptr, nullptr, slot_of_pos, e, rt, ct, cnt, off, ldsA, ldsB);
      __threadfence();
      __syncthreads();
      if (t == 0) atomicAdd(&upDone[e], 1);
    } else {
      // ---- down tile: out[token] += ew * (hid @ w2^T) ----
      block_wait(segB_done, SEGB_ITEMS);
      int gd = g - NU;
      int e = 0;
#pragma unroll
      for (int q = 1; q < NEXP; ++q) e += (gd >= prD[q]);
      int base = 0, cnt = 0, off = 0;
#pragma unroll
      for (int q = 0; q < NEXP; ++q)
        if (e == q) { base = prD[q]; cnt = cnts[q]; off = offs[q]; }
      int local = gd - base;
      int rt = local / (DDIM / 128), ct = local % (DDIM / 128);
      // all of expert e's up tiles must be complete
      block_wait(&upDone[e], ((cnt + 127) >> 7) * (HDIM / 128));
      gemm_tile<HDIM, DDIM, DDIM / 128, false, 1>(
          hid, w2b, nullptr, out, ew, slot_of_pos, e, rt, ct, cnt, off, ldsA, ldsB);
      // nothing gates on down-tile completion
    }
  }
}

extern "C" void kernel_launch(void* const* d_in, const int* in_sizes, int n_in,
                              void* d_out, int out_size, void* d_ws, size_t ws_size,
                              hipStream_t stream)
{
  const float* x  = (const float*)d_in[0];
  const int* eidx = (const int*)d_in[1];
  const float* ew = (const float*)d_in[2];
  const float* w1 = (const float*)d_in[3];
  const float* w2 = (const float*)d_in[4];
  float* out = (float*)d_out;

  char* ws = (char*)d_ws;
  // layout (bytes):
  //   [0,         16777216)  xb   (8192x1024 bf16)
  //   [16777216,  50331648)  w1b  (8x2048x1024 bf16)
  //   [50331648,  83886080)  w2b  (8x1024x2048 bf16)
  //   [83886080, 150994944)  hid  (16384x2048 bf16)
  //   [150994944, ...)       counts[8], offsets[8], slot_of_pos[16384], ctrs[16]
  unsigned short* xb  = (unsigned short*)ws;
  unsigned short* w1b = (unsigned short*)(ws + (size_t)16777216);
  unsigned short* w2b = (unsigned short*)(ws + (size_t)50331648);
  unsigned short* hid = (unsigned short*)(ws + (size_t)83886080);
  int* counts      = (int*)(ws + (size_t)150994944);
  int* offsets     = counts + NEXP;
  int* slot_of_pos = offsets + NEXP;
  int* ctrs        = slot_of_pos + NSLOTS;

  k_zero<<<256, 256, 0, stream>>>(out, ctrs);
  k_moe<<<1024, 256, 0, stream>>>(x, eidx, ew, w1, w2, out,
                                  xb, w1b, w2b, hid,
                                  counts, offsets, slot_of_pos, ctrs);
}

// Round 5
// 251.930 us; speedup vs baseline: 9.1577x; 9.1577x over previous
//
#include <hip/hip_runtime.h>
#include <hip/hip_bf16.h>
#include <stdint.h>

#define N_TOK   8192
#define DDIM    1024
#define HDIM    2048
#define NEXP    8
#define TOPK    2
#define NSLOTS  (N_TOK * TOPK)

typedef float f32x4 __attribute__((ext_vector_type(4)));
typedef __bf16 b16x8 __attribute__((ext_vector_type(8)));

__device__ __forceinline__ unsigned short f2bf(float f) {
  union { float f; uint32_t u; } x; x.f = f;
  uint32_t r = (x.u + 0x7FFFu + ((x.u >> 16) & 1u)) >> 16;
  return (unsigned short)r;
}
__device__ __forceinline__ float bf2f(unsigned short u) {
  union { uint32_t u; float f; } x; x.u = ((uint32_t)u) << 16; return x.f;
}

#define GLD16(gp, lp) __builtin_amdgcn_global_load_lds( \
    (const __attribute__((address_space(1))) void*)(gp), \
    (__attribute__((address_space(3))) void*)(lp), 16, 0, 0)

#define SCHED_FENCE() __builtin_amdgcn_sched_barrier(0)
#define RAW_BARRIER() { SCHED_FENCE(); __builtin_amdgcn_s_barrier(); SCHED_FENCE(); }

// ---------------- routing: one block does count + scan + scatter ----------------
__global__ void k_route(const int* __restrict__ idx, int* __restrict__ counts,
                        int* __restrict__ offsets,
                        int* __restrict__ slot_of_pos, int* __restrict__ pos_of_slot) {
  __shared__ int sc[NEXP], so[NEXP], scur[NEXP];
  int t = threadIdx.x;
  if (t < NEXP) sc[t] = 0;
  __syncthreads();
  for (int s = t; s < NSLOTS; s += 1024) atomicAdd(&sc[idx[s]], 1);
  __syncthreads();
  if (t == 0) {
    int o = 0;
    for (int e = 0; e < NEXP; ++e) { so[e] = o; scur[e] = o; o += sc[e]; }
  }
  __syncthreads();
  for (int s = t; s < NSLOTS; s += 1024) {
    int e = idx[s];
    int p = atomicAdd(&scur[e], 1);
    slot_of_pos[p] = s;
    pos_of_slot[s] = p;
  }
  if (t < NEXP) { counts[t] = sc[t]; offsets[t] = so[t]; }
}

// ---------------- fp32 -> bf16 conversion, all three tensors in one launch ----------------
__global__ void k_cvt3(const float* __restrict__ s0, const float* __restrict__ s1,
                       const float* __restrict__ s2, unsigned short* __restrict__ d0,
                       unsigned short* __restrict__ d1, unsigned short* __restrict__ d2,
                       int n0, int n1, int n2) {
  int stride = gridDim.x * blockDim.x;
  int tot = n0 + n1 + n2;
  for (int i = blockIdx.x * blockDim.x + threadIdx.x; i < tot; i += stride) {
    const float* s; unsigned short* d; int j;
    if (i < n0)            { s = s0; d = d0; j = i; }
    else if (i < n0 + n1)  { s = s1; d = d1; j = i - n0; }
    else                   { s = s2; d = d2; j = i - n0 - n1; }
    float4 a = ((const float4*)s)[2 * j];
    float4 b = ((const float4*)s)[2 * j + 1];
    union { unsigned short u[8]; uint4 v; } o;
    o.u[0] = f2bf(a.x); o.u[1] = f2bf(a.y); o.u[2] = f2bf(a.z); o.u[3] = f2bf(a.w);
    o.u[4] = f2bf(b.x); o.u[5] = f2bf(b.y); o.u[6] = f2bf(b.z); o.u[7] = f2bf(b.w);
    ((uint4*)d)[j] = o.v;
  }
}

// ---------------- grouped GEMM (NT): C[r,c] = A[r,:K] . B[c,:K] ----------------
// 128x128 tile, BK=64, 4 waves (each 64x64 = 4x4 frags of 16x16x32 bf16).
// NEW vs R2: double-buffered LDS (2x32KB) with counted vmcnt + raw s_barrier
// (T3-min + T4): stage(t+2) overlaps MFMA(t); vmcnt never drains to 0 in the
// steady state. Per-wave stage group = 8 gld16; at iter end outstanding =
// {t+1,t+2} = 16 -> s_waitcnt vmcnt(8) guarantees t+1 landed (FIFO).
// LDS XOR-swizzle byte^((row&7)<<4); inverse swizzle pre-applied to the GLOBAL
// source (rule #21). T5 setprio around the MFMA cluster.
template<int K, int NCOLS, bool GATHER, bool RELU2>
__global__ __launch_bounds__(256, 2)
void k_gemm(const unsigned short* __restrict__ A,
            const unsigned short* __restrict__ B,
            unsigned short* __restrict__ C,
            const int* __restrict__ counts,
            const int* __restrict__ offsets,
            const int* __restrict__ slot_of_pos)
{
  const int e   = blockIdx.z;
  const int cnt = counts[e];
  const int rt  = blockIdx.y;
  if (rt * 128 >= cnt) return;
  const int ct  = blockIdx.x;
  const int off = offsets[e];

  // dbuf layout (elements): buf0: A@0 B@8192 ; buf1: A@16384 B@24576
  __shared__ unsigned short lds[4 * 8192];   // 64 KiB

  const int t    = threadIdx.x;
  const int lane = t & 63;
  const int wid  = t >> 6;

  const unsigned short* Bexp = B + (size_t)e * NCOLS * K;

  // staging geometry: 16 chunks of 1 KiB per tensor; chunk = j*4 + wid
  const unsigned short* aSrc[4];
  const unsigned short* bSrc[4];
  int dOffE[4];                                  // element offset of chunk within a tensor tile
#pragma unroll
  for (int j = 0; j < 4; ++j) {
    const int chunk = j * 4 + wid;               // 0..15 (wave-uniform)
    const int row   = chunk * 8 + (lane >> 3);   // LDS row 0..127
    const int qcol  = ((lane & 7) * 16) ^ ((row & 7) << 4);  // pre-swizzled byte in row
    int pr  = rt * 128 + row;
    int prc = pr < cnt ? pr : 0;
    if constexpr (GATHER) {
      int tok = slot_of_pos[off + prc] >> 1;     // slot -> token (K=2)
      aSrc[j] = A + (size_t)tok * K + (qcol >> 1);
    } else {
      aSrc[j] = A + (size_t)(off + prc) * K + (qcol >> 1);
    }
    bSrc[j] = Bexp + (size_t)(ct * 128 + row) * K + (qcol >> 1);
    dOffE[j] = chunk * 512;                      // 1024 B / 2
  }

  const int wr = wid >> 1, wc = wid & 1;
  const int kq = (lane >> 4) * 16;
  int aByte[4], bByte[4], aXor[4], bXor[4];
#pragma unroll
  for (int m = 0; m < 4; ++m) {
    int row = wr * 64 + m * 16 + (lane & 15);
    aByte[m] = row * 128; aXor[m] = (row & 7) << 4;
    int col = wc * 64 + m * 16 + (lane & 15);
    bByte[m] = col * 128; bXor[m] = (col & 7) << 4;
  }

  f32x4 acc[4][4];
#pragma unroll
  for (int m = 0; m < 4; ++m)
#pragma unroll
    for (int n = 0; n < 4; ++n) acc[m][n] = (f32x4){0.f, 0.f, 0.f, 0.f};

  // stage tile tt into buffer (tt&1): 8 gld16 per thread (4 A + 4 B)
  auto STAGE = [&](int tt) {
    unsigned short* base = lds + ((tt & 1) << 14);   // 16384 elements per buf set
#pragma unroll
    for (int j = 0; j < 4; ++j) {
      GLD16(aSrc[j] + tt * 64, base + dOffE[j]);
      GLD16(bSrc[j] + tt * 64, base + 8192 + dOffE[j]);
    }
  };

  constexpr int KT = K / 64;

  // prologue: tiles 0 and 1 in flight; wait tile 0 (leave 8 outstanding)
  STAGE(0);
  STAGE(1);
  asm volatile("s_waitcnt vmcnt(8)" ::: "memory");
  RAW_BARRIER();

  for (int kt = 0; kt < KT; ++kt) {
    const char* cb = (const char*)(lds) + ((kt & 1) << 15);   // 32768 B per buf set
    b16x8 a0[4], b0[4], a1[4], b1[4];
#pragma unroll
    for (int m = 0; m < 4; ++m) {
      a0[m] = *(const b16x8*)(cb + aByte[m] + (kq ^ aXor[m]));
      a1[m] = *(const b16x8*)(cb + aByte[m] + ((64 + kq) ^ aXor[m]));
      b0[m] = *(const b16x8*)(cb + 16384 + bByte[m] + (kq ^ bXor[m]));
      b1[m] = *(const b16x8*)(cb + 16384 + bByte[m] + ((64 + kq) ^ bXor[m]));
    }
    asm volatile("s_waitcnt lgkmcnt(0)" ::: "memory");
    SCHED_FENCE();                    // rule #18: no MFMA hoist above the wait
    RAW_BARRIER();                    // all waves done reading buf[kt&1]
    if (kt + 2 < KT) STAGE(kt + 2);   // overwrite buf[kt&1]; lands during MFMA(t)..(t+1)
    SCHED_FENCE();
    __builtin_amdgcn_s_setprio(1);
#pragma unroll
    for (int m = 0; m < 4; ++m)
#pragma unroll
      for (int n = 0; n < 4; ++n)
        acc[m][n] = __builtin_amdgcn_mfma_f32_16x16x32_bf16(a0[m], b0[n], acc[m][n], 0, 0, 0);
#pragma unroll
    for (int m = 0; m < 4; ++m)
#pragma unroll
      for (int n = 0; n < 4; ++n)
        acc[m][n] = __builtin_amdgcn_mfma_f32_16x16x32_bf16(a1[m], b1[n], acc[m][n], 0, 0, 0);
    __builtin_amdgcn_s_setprio(0);
    SCHED_FENCE();
    if (kt < KT - 2) {
      asm volatile("s_waitcnt vmcnt(8)" ::: "memory");   // tile t+1 landed; t+2 may fly
      RAW_BARRIER();
    } else if (kt == KT - 2) {
      asm volatile("s_waitcnt vmcnt(0)" ::: "memory");   // last tile: nothing behind it
      RAW_BARRIER();
    }
    // kt == KT-1: fall through to epilogue
  }

  // epilogue: C/D layout col = lane&15, row = (lane>>4)*4 + r  (m89-verified)
  const int rbase = rt * 128 + wr * 64 + (lane >> 4) * 4;
  const int cbase = ct * 128 + wc * 64 + (lane & 15);
#pragma unroll
  for (int m = 0; m < 4; ++m) {
#pragma unroll
    for (int r = 0; r < 4; ++r) {
      int pr = rbase + m * 16 + r;
      if (pr < cnt) {
        unsigned short* crow = C + (size_t)(off + pr) * NCOLS + cbase;
#pragma unroll
        for (int n = 0; n < 4; ++n) {
          float v = acc[m][n][r];
          if (RELU2) v = v > 0.f ? v * v : 0.f;
          crow[n * 16] = f2bf(v);
        }
      }
    }
  }
}

// ---------------- weighted combine of the two slots per token ----------------
__global__ void k_combine(const unsigned short* __restrict__ oslt,
                          const int* __restrict__ pos_of_slot,
                          const float* __restrict__ ew,
                          float* __restrict__ out)
{
  int n = blockIdx.x;
  int d = threadIdx.x * 4;
  int p0 = pos_of_slot[2 * n];
  int p1 = pos_of_slot[2 * n + 1];
  float w0 = ew[2 * n], w1 = ew[2 * n + 1];
  ushort4 a = *(const ushort4*)(oslt + (size_t)p0 * DDIM + d);
  ushort4 b = *(const ushort4*)(oslt + (size_t)p1 * DDIM + d);
  float4 o;
  o.x = w0 * bf2f(a.x) + w1 * bf2f(b.x);
  o.y = w0 * bf2f(a.y) + w1 * bf2f(b.y);
  o.z = w0 * bf2f(a.z) + w1 * bf2f(b.z);
  o.w = w0 * bf2f(a.w) + w1 * bf2f(b.w);
  *(float4*)(out + (size_t)n * DDIM + d) = o;
}

extern "C" void kernel_launch(void* const* d_in, const int* in_sizes, int n_in,
                              void* d_out, int out_size, void* d_ws, size_t ws_size,
                              hipStream_t stream)
{
  const float* x  = (const float*)d_in[0];
  const int* eidx = (const int*)d_in[1];
  const float* ew = (const float*)d_in[2];
  const float* w1 = (const float*)d_in[3];
  const float* w2 = (const float*)d_in[4];
  float* out = (float*)d_out;

  char* ws = (char*)d_ws;
  // layout (bytes):
  //   [0,            16777216)  xb   (8192x1024 bf16)          } dead after up-GEMM
  //   [16777216,     50331648)  w1b  (8x2048x1024 bf16)        }
  //   [0,            33554432)  oslt (16384x1024 bf16)  -- aliases xb+w1b, live after up-GEMM
  //   [50331648,     83886080)  w2b  (8x1024x2048 bf16)
  //   [83886080,    150994944)  hid  (16384x2048 bf16)
  //   [150994944,  ...       )  routing ints
  unsigned short* xb   = (unsigned short*)ws;
  unsigned short* w1b  = (unsigned short*)(ws + (size_t)16777216);
  unsigned short* oslt = (unsigned short*)ws;
  unsigned short* w2b  = (unsigned short*)(ws + (size_t)50331648);
  unsigned short* hid  = (unsigned short*)(ws + (size_t)83886080);
  int* counts      = (int*)(ws + (size_t)150994944);
  int* offsets     = counts + NEXP;
  int* slot_of_pos = offsets + NEXP;
  int* pos_of_slot = slot_of_pos + NSLOTS;

  k_route<<<1, 1024, 0, stream>>>(eidx, counts, offsets, slot_of_pos, pos_of_slot);

  k_cvt3<<<2048, 256, 0, stream>>>(x, w1, w2, xb, w1b, w2b,
                                   N_TOK * DDIM / 8, NEXP * HDIM * DDIM / 8, NEXP * DDIM * HDIM / 8);

  dim3 gup(HDIM / 128, 128, NEXP);
  k_gemm<DDIM, HDIM, true,  true ><<<gup, 256, 0, stream>>>(xb,  w1b, hid,  counts, offsets, slot_of_pos);
  dim3 gdn(DDIM / 128, 128, NEXP);
  k_gemm<HDIM, DDIM, false, false><<<gdn, 256, 0, stream>>>(hid, w2b, oslt, counts, offsets, slot_of_pos);

  k_combine<<<N_TOK, 256, 0, stream>>>(oslt, pos_of_slot, ew, out);
}

// Round 6
// 250.763 us; speedup vs baseline: 9.2004x; 1.0047x over previous
//
#include <hip/hip_runtime.h>
#include <hip/hip_bf16.h>
#include <stdint.h>

#define N_TOK   8192
#define DDIM    1024
#define HDIM    2048
#define NEXP    8
#define TOPK    2
#define NSLOTS  (N_TOK * TOPK)

typedef float f32x4 __attribute__((ext_vector_type(4)));
typedef __bf16 b16x8 __attribute__((ext_vector_type(8)));

__device__ __forceinline__ unsigned short f2bf(float f) {
  union { float f; uint32_t u; } x; x.f = f;
  uint32_t r = (x.u + 0x7FFFu + ((x.u >> 16) & 1u)) >> 16;
  return (unsigned short)r;
}
__device__ __forceinline__ float bf2f(unsigned short u) {
  union { uint32_t u; float f; } x; x.u = ((uint32_t)u) << 16; return x.f;
}

#define GLD16(gp, lp) __builtin_amdgcn_global_load_lds( \
    (const __attribute__((address_space(1))) void*)(gp), \
    (__attribute__((address_space(3))) void*)(lp), 16, 0, 0)

#define SCHED_FENCE() __builtin_amdgcn_sched_barrier(0)
#define RAW_BARRIER() { SCHED_FENCE(); __builtin_amdgcn_s_barrier(); SCHED_FENCE(); }

// ---------------- routing: one block does count + scan + scatter ----------------
__global__ void k_route(const int* __restrict__ idx, int* __restrict__ counts,
                        int* __restrict__ offsets,
                        int* __restrict__ slot_of_pos, int* __restrict__ pos_of_slot) {
  __shared__ int sc[NEXP], so[NEXP], scur[NEXP];
  int t = threadIdx.x;
  if (t < NEXP) sc[t] = 0;
  __syncthreads();
  for (int s = t; s < NSLOTS; s += 1024) atomicAdd(&sc[idx[s]], 1);
  __syncthreads();
  if (t == 0) {
    int o = 0;
    for (int e = 0; e < NEXP; ++e) { so[e] = o; scur[e] = o; o += sc[e]; }
  }
  __syncthreads();
  for (int s = t; s < NSLOTS; s += 1024) {
    int e = idx[s];
    int p = atomicAdd(&scur[e], 1);
    slot_of_pos[p] = s;
    pos_of_slot[s] = p;
  }
  if (t < NEXP) { counts[t] = sc[t]; offsets[t] = so[t]; }
}

// ---------------- fp32 -> bf16 conversion, all three tensors in one launch ----------------
__global__ void k_cvt3(const float* __restrict__ s0, const float* __restrict__ s1,
                       const float* __restrict__ s2, unsigned short* __restrict__ d0,
                       unsigned short* __restrict__ d1, unsigned short* __restrict__ d2,
                       int n0, int n1, int n2) {
  int stride = gridDim.x * blockDim.x;
  int tot = n0 + n1 + n2;
  for (int i = blockIdx.x * blockDim.x + threadIdx.x; i < tot; i += stride) {
    const float* s; unsigned short* d; int j;
    if (i < n0)            { s = s0; d = d0; j = i; }
    else if (i < n0 + n1)  { s = s1; d = d1; j = i - n0; }
    else                   { s = s2; d = d2; j = i - n0 - n1; }
    float4 a = ((const float4*)s)[2 * j];
    float4 b = ((const float4*)s)[2 * j + 1];
    union { unsigned short u[8]; uint4 v; } o;
    o.u[0] = f2bf(a.x); o.u[1] = f2bf(a.y); o.u[2] = f2bf(a.z); o.u[3] = f2bf(a.w);
    o.u[4] = f2bf(b.x); o.u[5] = f2bf(b.y); o.u[6] = f2bf(b.z); o.u[7] = f2bf(b.w);
    ((uint4*)d)[j] = o.v;
  }
}

// ---------------- grouped GEMM (NT): C[r,c] = A[r,:K] . B[c,:K] ----------------
// 128x128 tile, BK=64, 4 waves (each 64x64 = 4x4 frags of 16x16x32 bf16).
// Double-buffered LDS with counted vmcnt + raw s_barrier (T4), PLUS a 2-stage
// register ping-pong at the half-K-step level: each 8-ds_read group has a
// 16-MFMA cluster of the *other* half overlapping its latency (T3-style
// fine interleave; R5's all-reads-then-all-MFMA left reads serial -> 30% MfmaUtil).
// vmcnt accounting (per wave, 8 gld16 per STAGE): outstanding at the wait is
// {tile kt+1 remnants, tile kt+2} <= 16 -> vmcnt(8) guarantees kt+1 landed.
// LDS XOR-swizzle byte^((row&7)<<4); inverse swizzle pre-applied to the GLOBAL
// source (rule #21). T5 setprio around MFMA clusters.
template<int K, int NCOLS, bool GATHER, bool RELU2>
__global__ __launch_bounds__(256, 2)
void k_gemm(const unsigned short* __restrict__ A,
            const unsigned short* __restrict__ B,
            unsigned short* __restrict__ C,
            const int* __restrict__ counts,
            const int* __restrict__ offsets,
            const int* __restrict__ slot_of_pos)
{
  const int e   = blockIdx.z;
  const int cnt = counts[e];
  const int rt  = blockIdx.y;
  if (rt * 128 >= cnt) return;
  const int ct  = blockIdx.x;
  const int off = offsets[e];

  // dbuf layout (elements): buf0: A@0 B@8192 ; buf1: A@16384 B@24576
  __shared__ unsigned short lds[4 * 8192];   // 64 KiB

  const int t    = threadIdx.x;
  const int lane = t & 63;
  const int wid  = t >> 6;

  const unsigned short* Bexp = B + (size_t)e * NCOLS * K;

  // staging geometry: 16 chunks of 1 KiB per tensor; chunk = j*4 + wid
  const unsigned short* aSrc[4];
  const unsigned short* bSrc[4];
  int dOffE[4];
#pragma unroll
  for (int j = 0; j < 4; ++j) {
    const int chunk = j * 4 + wid;               // 0..15 (wave-uniform)
    const int row   = chunk * 8 + (lane >> 3);   // LDS row 0..127
    const int qcol  = ((lane & 7) * 16) ^ ((row & 7) << 4);  // pre-swizzled byte in row
    int pr  = rt * 128 + row;
    int prc = pr < cnt ? pr : 0;
    if constexpr (GATHER) {
      int tok = slot_of_pos[off + prc] >> 1;     // slot -> token (K=2)
      aSrc[j] = A + (size_t)tok * K + (qcol >> 1);
    } else {
      aSrc[j] = A + (size_t)(off + prc) * K + (qcol >> 1);
    }
    bSrc[j] = Bexp + (size_t)(ct * 128 + row) * K + (qcol >> 1);
    dOffE[j] = chunk * 512;                      // 1024 B / 2
  }

  const int wr = wid >> 1, wc = wid & 1;
  const int kq = (lane >> 4) * 16;
  int aByte[4], bByte[4], aXor[4], bXor[4];
#pragma unroll
  for (int m = 0; m < 4; ++m) {
    int row = wr * 64 + m * 16 + (lane & 15);
    aByte[m] = row * 128; aXor[m] = (row & 7) << 4;
    int col = wc * 64 + m * 16 + (lane & 15);
    bByte[m] = col * 128; bXor[m] = (col & 7) << 4;
  }

  f32x4 acc[4][4];
#pragma unroll
  for (int m = 0; m < 4; ++m)
#pragma unroll
    for (int n = 0; n < 4; ++n) acc[m][n] = (f32x4){0.f, 0.f, 0.f, 0.f};

  // stage tile tt into buffer (tt&1): 8 gld16 per thread (4 A + 4 B)
  auto STAGE = [&](int tt) {
    unsigned short* base = lds + ((tt & 1) << 14);
#pragma unroll
    for (int j = 0; j < 4; ++j) {
      GLD16(aSrc[j] + tt * 64, base + dOffE[j]);
      GLD16(bSrc[j] + tt * 64, base + 8192 + dOffE[j]);
    }
  };

  b16x8 a0[4], b0[4], a1[4], b1[4];

#define READ_KS0(CB) do { _Pragma("unroll") \
  for (int m_ = 0; m_ < 4; ++m_) { \
    a0[m_] = *(const b16x8*)((CB) + aByte[m_] + (kq ^ aXor[m_])); \
    b0[m_] = *(const b16x8*)((CB) + 16384 + bByte[m_] + (kq ^ bXor[m_])); \
  } } while (0)

#define READ_KS1(CB) do { _Pragma("unroll") \
  for (int m_ = 0; m_ < 4; ++m_) { \
    a1[m_] = *(const b16x8*)((CB) + aByte[m_] + ((64 + kq) ^ aXor[m_])); \
    b1[m_] = *(const b16x8*)((CB) + 16384 + bByte[m_] + ((64 + kq) ^ bXor[m_])); \
  } } while (0)

#define MFMA16(A_, B_) do { _Pragma("unroll") \
  for (int m_ = 0; m_ < 4; ++m_) _Pragma("unroll") \
    for (int n_ = 0; n_ < 4; ++n_) \
      acc[m_][n_] = __builtin_amdgcn_mfma_f32_16x16x32_bf16(A_[m_], B_[n_], acc[m_][n_], 0, 0, 0); \
  } while (0)

  constexpr int KT = K / 64;

  // prologue: tiles 0,1 in flight; wait tile 0 (leave tile 1's 8 outstanding)
  STAGE(0);
  STAGE(1);
  asm volatile("s_waitcnt vmcnt(8)" ::: "memory");
  RAW_BARRIER();
  {
    const char* cb = (const char*)lds;
    READ_KS0(cb);                                // 8 reads in flight
  }
  SCHED_FENCE();

  for (int kt = 0; kt < KT; ++kt) {
    const char* cb0 = (const char*)lds + ((kt & 1) << 15);
    const char* cb1 = (const char*)lds + (((kt + 1) & 1) << 15);

    READ_KS1(cb0);                               // +8 -> 16 lgkm in flight
    asm volatile("s_waitcnt lgkmcnt(8)" ::: "memory");   // ks0 frags ready
    SCHED_FENCE();
    __builtin_amdgcn_s_setprio(1);
    MFMA16(a0, b0);                              // overlaps ks1-read latency
    __builtin_amdgcn_s_setprio(0);
    SCHED_FENCE();
    asm volatile("s_waitcnt lgkmcnt(0)" ::: "memory");   // ks1 ready; buf[kt] reads done
    SCHED_FENCE();
    RAW_BARRIER();                               // all waves done with buf[kt]
    if (kt + 2 < KT) STAGE(kt + 2);              // overwrite buf[kt]
    SCHED_FENCE();
    if (kt + 1 < KT) {
      if (kt + 2 < KT) {
        asm volatile("s_waitcnt vmcnt(8)" ::: "memory"); // tile kt+1 landed
      } else {
        asm volatile("s_waitcnt vmcnt(0)" ::: "memory"); // last staged tile
      }
      RAW_BARRIER();                             // buf[kt+1] ready for all
      READ_KS0(cb1);                             // next ks0, 8 reads in flight
      SCHED_FENCE();
    }
    __builtin_amdgcn_s_setprio(1);
    MFMA16(a1, b1);                              // overlaps next ks0-read latency
    __builtin_amdgcn_s_setprio(0);
    SCHED_FENCE();
  }

#undef READ_KS0
#undef READ_KS1
#undef MFMA16

  // epilogue: C/D layout col = lane&15, row = (lane>>4)*4 + r  (m89-verified)
  const int rbase = rt * 128 + wr * 64 + (lane >> 4) * 4;
  const int cbase = ct * 128 + wc * 64 + (lane & 15);
#pragma unroll
  for (int m = 0; m < 4; ++m) {
#pragma unroll
    for (int r = 0; r < 4; ++r) {
      int pr = rbase + m * 16 + r;
      if (pr < cnt) {
        unsigned short* crow = C + (size_t)(off + pr) * NCOLS + cbase;
#pragma unroll
        for (int n = 0; n < 4; ++n) {
          float v = acc[m][n][r];
          if (RELU2) v = v > 0.f ? v * v : 0.f;
          crow[n * 16] = f2bf(v);
        }
      }
    }
  }
}

// ---------------- weighted combine of the two slots per token ----------------
__global__ void k_combine(const unsigned short* __restrict__ oslt,
                          const int* __restrict__ pos_of_slot,
                          const float* __restrict__ ew,
                          float* __restrict__ out)
{
  int n = blockIdx.x;
  int d = threadIdx.x * 4;
  int p0 = pos_of_slot[2 * n];
  int p1 = pos_of_slot[2 * n + 1];
  float w0 = ew[2 * n], w1 = ew[2 * n + 1];
  ushort4 a = *(const ushort4*)(oslt + (size_t)p0 * DDIM + d);
  ushort4 b = *(const ushort4*)(oslt + (size_t)p1 * DDIM + d);
  float4 o;
  o.x = w0 * bf2f(a.x) + w1 * bf2f(b.x);
  o.y = w0 * bf2f(a.y) + w1 * bf2f(b.y);
  o.z = w0 * bf2f(a.z) + w1 * bf2f(b.z);
  o.w = w0 * bf2f(a.w) + w1 * bf2f(b.w);
  *(float4*)(out + (size_t)n * DDIM + d) = o;
}

extern "C" void kernel_launch(void* const* d_in, const int* in_sizes, int n_in,
                              void* d_out, int out_size, void* d_ws, size_t ws_size,
                              hipStream_t stream)
{
  const float* x  = (const float*)d_in[0];
  const int* eidx = (const int*)d_in[1];
  const float* ew = (const float*)d_in[2];
  const float* w1 = (const float*)d_in[3];
  const float* w2 = (const float*)d_in[4];
  float* out = (float*)d_out;

  char* ws = (char*)d_ws;
  // layout (bytes):
  //   [0,            16777216)  xb   (8192x1024 bf16)          } dead after up-GEMM
  //   [16777216,     50331648)  w1b  (8x2048x1024 bf16)        }
  //   [0,            33554432)  oslt (16384x1024 bf16)  -- aliases xb+w1b, live after up-GEMM
  //   [50331648,     83886080)  w2b  (8x1024x2048 bf16)
  //   [83886080,    150994944)  hid  (16384x2048 bf16)
  //   [150994944,  ...       )  routing ints
  unsigned short* xb   = (unsigned short*)ws;
  unsigned short* w1b  = (unsigned short*)(ws + (size_t)16777216);
  unsigned short* oslt = (unsigned short*)ws;
  unsigned short* w2b  = (unsigned short*)(ws + (size_t)50331648);
  unsigned short* hid  = (unsigned short*)(ws + (size_t)83886080);
  int* counts      = (int*)(ws + (size_t)150994944);
  int* offsets     = counts + NEXP;
  int* slot_of_pos = offsets + NEXP;
  int* pos_of_slot = slot_of_pos + NSLOTS;

  k_route<<<1, 1024, 0, stream>>>(eidx, counts, offsets, slot_of_pos, pos_of_slot);

  k_cvt3<<<2048, 256, 0, stream>>>(x, w1, w2, xb, w1b, w2b,
                                   N_TOK * DDIM / 8, NEXP * HDIM * DDIM / 8, NEXP * DDIM * HDIM / 8);

  dim3 gup(HDIM / 128, 128, NEXP);
  k_gemm<DDIM, HDIM, true,  true ><<<gup, 256, 0, stream>>>(xb,  w1b, hid,  counts, offsets, slot_of_pos);
  dim3 gdn(DDIM / 128, 128, NEXP);
  k_gemm<HDIM, DDIM, false, false><<<gdn, 256, 0, stream>>>(hid, w2b, oslt, counts, offsets, slot_of_pos);

  k_combine<<<N_TOK, 256, 0, stream>>>(oslt, pos_of_slot, ew, out);
}